// Round 1
// baseline (561.046 us; speedup 1.0000x reference)
//
#include <hip/hip_runtime.h>

#define NN 512          // N == M
#define DD 64           // feature dim
#define DQ 16           // DD/4
#define YST 68          // LDS row stride in floats (64 data + 4 pad; pad[0] = ||y||^2)
#define BIGF 1e10f

// One DP step over anti-diagonal d. Thread t owns row i=t.
// a1 = diag d-1 values, a2 = diag d-2 values, aw = write target (diag d).
// Arrays are length NN+1 with slot 0 the permanent BIG boundary (i = -1).
__device__ __forceinline__ void dtw_step(
    const int d, const int t, const float4* __restrict__ xr, const float xx,
    const float* __restrict__ ylds,
    const float* __restrict__ a1, const float* __restrict__ a2,
    float* __restrict__ aw, float& myP1)
{
  const int j = d - t;
  const bool valid = (j >= 0) && (j < NN);
  float dd = 0.f;
  if (valid) {
    const float* yrow = &ylds[j * YST];
    float ax = 0.f, ay = 0.f, az = 0.f, aww = 0.f;
    #pragma unroll
    for (int k = 0; k < DQ; ++k) {
      float4 v = *(const float4*)(yrow + 4 * k);
      ax  = fmaf(xr[k].x, v.x, ax);
      ay  = fmaf(xr[k].y, v.y, ay);
      az  = fmaf(xr[k].z, v.z, az);
      aww = fmaf(xr[k].w, v.w, aww);
    }
    float dot = (ax + ay) + (az + aww);
    dd = fmaf(-2.f, dot, xx + yrow[DD]);   // ||x_i||^2 + ||y_j||^2 - 2 dot
  }
  // neighbors: (i-1, j) from diag d-1, (i-1, j-1) from diag d-2, (i, j-1) = own reg
  float p1m1 = a1[t];
  float p2m1 = a2[t];
  if (t == 0) p2m1 = (d == 0) ? 0.f : BIGF;   // R[-1][-1]=0 only at the corner
  float m = fminf(fminf(p2m1, p1m1), myP1);
  float s = __expf(m - p2m1) + __expf(m - p1m1) + __expf(m - myP1);
  float sm = m - __logf(s);                    // softmin, gamma = 1
  float cur = valid ? (dd + sm) : BIGF;
  aw[t + 1] = cur;
  myP1 = cur;
  __syncthreads();
}

__global__ __launch_bounds__(512, 2)
void dtw_kernel(const float* __restrict__ X, const float* __restrict__ Y,
                float* __restrict__ loss)
{
  __shared__ float ylds[NN * YST];        // 139264 B
  __shared__ float diag[3][NN + 1];       // 6156 B rotating anti-diagonals

  const int b = blockIdx.x;
  const int t = threadIdx.x;

  // stage y[b] into LDS (padded rows), coalesced float4 loads
  const float4* Y4 = (const float4*)(Y + (size_t)b * NN * DD);
  for (int idx = t; idx < NN * DQ; idx += NN) {
    float4 v = Y4[idx];
    *(float4*)&ylds[(idx >> 4) * YST + (idx & 15) * 4] = v;
  }
  diag[0][t + 1] = BIGF; diag[1][t + 1] = BIGF; diag[2][t + 1] = BIGF;
  if (t == 0) { diag[0][0] = BIGF; diag[1][0] = BIGF; diag[2][0] = BIGF; }
  __syncthreads();

  // x row t -> registers, plus ||x_t||^2 ; ||y_t||^2 -> pad slot
  float4 xr[DQ];
  float xx = 0.f;
  const float4* X4 = (const float4*)(X + (size_t)b * NN * DD + (size_t)t * DD);
  #pragma unroll
  for (int k = 0; k < DQ; ++k) {
    float4 v = X4[k];
    xr[k] = v;
    xx += v.x * v.x + v.y * v.y + v.z * v.z + v.w * v.w;
  }
  {
    float s = 0.f;
    const float* yrow = &ylds[t * YST];
    #pragma unroll
    for (int k = 0; k < DQ; ++k) {
      float4 v = *(const float4*)(yrow + 4 * k);
      s += v.x * v.x + v.y * v.y + v.z * v.z + v.w * v.w;
    }
    ylds[t * YST + DD] = s;
  }
  __syncthreads();

  float myP1 = BIGF;
  // 1023 diagonals = 341 * 3, unrolled x3 so rotation indices are static.
  // At diag d: write diag[d%3], read a1=diag[(d+2)%3], a2=diag[(d+1)%3].
  for (int dbase = 0; dbase < 2 * NN - 1; dbase += 3) {
    dtw_step(dbase,     t, xr, xx, ylds, diag[2], diag[1], diag[0], myP1);
    dtw_step(dbase + 1, t, xr, xx, ylds, diag[0], diag[2], diag[1], myP1);
    dtw_step(dbase + 2, t, xr, xx, ylds, diag[1], diag[0], diag[2], myP1);
  }
  // thread 511 holds R[511][511] after d = 1022
  if (t == NN - 1) loss[b] = myP1;
}

__global__ void mean_kernel(const float* __restrict__ loss, float* __restrict__ out, int B)
{
  const int t = threadIdx.x;           // 64 threads, one wave
  float v = (t < B) ? loss[t] : 0.f;
  #pragma unroll
  for (int off = 32; off; off >>= 1) v += __shfl_down(v, off);
  if (t == 0) out[0] = v / (float)B;
}

extern "C" void kernel_launch(void* const* d_in, const int* in_sizes, int n_in,
                              void* d_out, int out_size, void* d_ws, size_t ws_size,
                              hipStream_t stream)
{
  const float* X = (const float*)d_in[0];
  const float* Y = (const float*)d_in[1];
  float* out = (float*)d_out;
  float* ws  = (float*)d_ws;          // per-batch losses (B floats)

  const int B = in_sizes[0] / (NN * DD);   // 64

  dtw_kernel<<<B, NN, 0, stream>>>(X, Y, ws);
  mean_kernel<<<1, 64, 0, stream>>>(ws, out, B);
}

// Round 2
// 321.390 us; speedup vs baseline: 1.7457x; 1.7457x over previous
//
#include <hip/hip_runtime.h>

#define NN 512          // N == M
#define DD 64           // feature dim
#define BIGF 1e10f

// ======================= Phase 1: delta -> skewed layout =======================
// skew[b][d][i] at  skew + ((size_t)b*1023 + d)*512 + i   (full 1023x512 slots,
// only valid i in [max(0,d-511), min(511,d)] are written; DP masks the rest).
#define TS 128          // tile size (i and j)
#define XST 68          // LDS stage row stride (floats), 16B-aligned rows
#define ZST 132         // LDS Zs row stride (floats), 16B-aligned, odd/4 rotation

__global__ __launch_bounds__(256, 2)
void delta_kernel(const float* __restrict__ X, const float* __restrict__ Y,
                  float* __restrict__ skew)
{
  __shared__ __align__(16) char smem[TS * XST * 4 * 2];   // 69632 B
  __shared__ float norms[2 * TS];                          // xx | yy
  float* Xs = (float*)smem;               // [TS][XST]
  float* Ys = Xs + TS * XST;              // [TS][XST]
  float* Zs = (float*)smem;               // [TS][ZST] overlays Xs|Ys (67584 B)

  const int b  = blockIdx.z;
  const int i0 = blockIdx.y * TS;
  const int j0 = blockIdx.x * TS;
  const int tid = threadIdx.x;

  // ---- stage X,Y tiles (row-major, padded stride) ----
  const float4* X4 = (const float4*)(X + ((size_t)b * NN + i0) * DD);
  const float4* Y4 = (const float4*)(Y + ((size_t)b * NN + j0) * DD);
  #pragma unroll
  for (int q = 0; q < 8; ++q) {
    int idx = tid + 256 * q;          // 0..2047
    int r = idx >> 4, c4 = idx & 15;
    *(float4*)&Xs[r * XST + 4 * c4] = X4[idx];
    *(float4*)&Ys[r * XST + 4 * c4] = Y4[idx];
  }
  __syncthreads();

  // ---- row norms: threads 0..127 -> xx, 128..255 -> yy ----
  {
    const float* row = (tid < TS) ? &Xs[tid * XST] : &Ys[(tid - TS) * XST];
    float s = 0.f;
    #pragma unroll
    for (int k4 = 0; k4 < 16; ++k4) {
      float4 v = *(const float4*)&row[4 * k4];
      s += v.x * v.x + v.y * v.y + v.z * v.z + v.w * v.w;
    }
    norms[tid] = s;
  }

  // ---- 8x8 register micro-tile dot products ----
  const int iB = (tid >> 4) * 8;
  const int jB = (tid & 15) * 8;
  float acc[8][8];
  #pragma unroll
  for (int a = 0; a < 8; ++a)
    #pragma unroll
    for (int c = 0; c < 8; ++c) acc[a][c] = 0.f;

  #pragma unroll
  for (int kc = 0; kc < 16; ++kc) {
    float4 xv[8], yv[8];
    #pragma unroll
    for (int a = 0; a < 8; ++a) xv[a] = *(const float4*)&Xs[(iB + a) * XST + 4 * kc];
    #pragma unroll
    for (int c = 0; c < 8; ++c) yv[c] = *(const float4*)&Ys[(jB + c) * XST + 4 * kc];
    #pragma unroll
    for (int a = 0; a < 8; ++a)
      #pragma unroll
      for (int c = 0; c < 8; ++c) {
        float4 xa = xv[a], yc = yv[c];
        acc[a][c] = fmaf(xa.x, yc.x,
                    fmaf(xa.y, yc.y,
                    fmaf(xa.z, yc.z,
                    fmaf(xa.w, yc.w, acc[a][c]))));
      }
  }
  __syncthreads();   // Xs/Ys dead; norms visible; Zs may overwrite

  // ---- delta into Zs ----
  #pragma unroll
  for (int a = 0; a < 8; ++a) {
    float xxv = norms[iB + a];
    float4 z0, z1;
    z0.x = fmaf(-2.f, acc[a][0], xxv + norms[TS + jB + 0]);
    z0.y = fmaf(-2.f, acc[a][1], xxv + norms[TS + jB + 1]);
    z0.z = fmaf(-2.f, acc[a][2], xxv + norms[TS + jB + 2]);
    z0.w = fmaf(-2.f, acc[a][3], xxv + norms[TS + jB + 3]);
    z1.x = fmaf(-2.f, acc[a][4], xxv + norms[TS + jB + 4]);
    z1.y = fmaf(-2.f, acc[a][5], xxv + norms[TS + jB + 5]);
    z1.z = fmaf(-2.f, acc[a][6], xxv + norms[TS + jB + 6]);
    z1.w = fmaf(-2.f, acc[a][7], xxv + norms[TS + jB + 7]);
    *(float4*)&Zs[(iB + a) * ZST + jB]     = z0;
    *(float4*)&Zs[(iB + a) * ZST + jB + 4] = z1;
  }
  __syncthreads();

  // ---- write out per-diagonal segments (coalesced) ----
  const int lane = tid & 63, w = tid >> 6;
  float* skb = skew + (size_t)b * 1023 * NN;
  const int dbase = i0 + j0;
  for (int e = w; e < 2 * TS - 1; e += 4) {
    int lo = (e > TS - 1) ? e - (TS - 1) : 0;
    int hi = (e < TS - 1) ? e : TS - 1;
    for (int il = lo + lane; il <= hi; il += 64) {
      float v = Zs[il * ZST + (e - il)];
      skb[(size_t)(dbase + e) * NN + (i0 + il)] = v;
    }
  }
}

// ======================= Phase 2: register-resident DP =======================
// 256 threads; thread t owns rows 2t (lo) and 2t+1 (hi). State in registers:
//   clo, chi   = own rows' values at diag d-1
//   clo2       = own lo row at d-2
//   n2         = neighbor row (2t-1) at d-2
// Cross-thread: one shfl_up per step; wave boundary via double-buffered edge LDS.
__device__ __forceinline__ void dp_step(int d, int p, int t, int lane, int w,
                                        float2 del, float (*edge)[8],
                                        float& clo, float& chi, float& clo2, float& n2)
{
  float nb = __shfl_up(chi, 1);        // row 2t-1 at d-1 (in-wave)
  float ev = edge[p][w];               // wave-boundary value (slot 0 = BIG const)
  if (lane == 0) nb = ev;

  int jlo = d - 2 * t;
  // lo cell (i=2t, j=jlo): diag=n2, up=nb, left=clo
  float m1 = fminf(fminf(n2, nb), clo);
  float s1 = __expf(m1 - n2) + __expf(m1 - nb) + __expf(m1 - clo);
  float lo = del.x + (m1 - __logf(s1));
  lo = ((unsigned)jlo < 512u) ? lo : BIGF;
  // hi cell (i=2t+1, j=jlo-1): diag=clo2, up=clo(d-1), left=chi
  float m2 = fminf(fminf(clo2, clo), chi);
  float s2 = __expf(m2 - clo2) + __expf(m2 - clo) + __expf(m2 - chi);
  float hi = del.y + (m2 - __logf(s2));
  hi = ((unsigned)(jlo - 1) < 512u) ? hi : BIGF;

  n2 = nb; clo2 = clo; clo = lo; chi = hi;
  if (lane == 63) edge[p ^ 1][w + 1] = hi;   // boundary for next step
  __syncthreads();
}

__global__ __launch_bounds__(256, 1)
void dp_kernel(const float* __restrict__ skew, float* __restrict__ loss)
{
  __shared__ float edge[2][8];
  const int b = blockIdx.x;
  const int t = threadIdx.x;
  const int lane = t & 63;
  const int w = t >> 6;

  if (t < 16) ((float*)edge)[t] = BIGF;
  __syncthreads();

  const float2* sk2 = (const float2*)(skew + (size_t)b * 1023 * NN) + t;

  float2 pf[8];
  #pragma unroll
  for (int q = 0; q < 8; ++q) pf[q] = sk2[(size_t)q * 256];

  float clo = BIGF, chi = BIGF, clo2 = BIGF;
  float n2 = (t == 0) ? 0.f : BIGF;    // corner: R[-1][-1]=0 at d=0

  for (int db = 0; db < 1016; db += 8) {
    #pragma unroll
    for (int q = 0; q < 8; ++q) {
      int d = db + q;
      float2 del = pf[q];
      dp_step(d, q & 1, t, lane, w, del, edge, clo, chi, clo2, n2);
      int dn = d + 8; if (dn > 1022) dn = 1022;   // clamped prefetch
      pf[q] = sk2[(size_t)dn * 256];
    }
  }
  #pragma unroll
  for (int q = 0; q < 7; ++q) {
    dp_step(1016 + q, q & 1, t, lane, w, pf[q], edge, clo, chi, clo2, n2);
  }

  if (t == 255) loss[b] = chi;         // R[511][511]
}

// ======================= Fallback (round-1 kernel) =======================
#define DQ 16
#define YST 68

__device__ __forceinline__ void fb_step(
    const int d, const int t, const float4* __restrict__ xr, const float xx,
    const float* __restrict__ ylds,
    const float* __restrict__ a1, const float* __restrict__ a2,
    float* __restrict__ aw, float& myP1)
{
  const int j = d - t;
  const bool valid = (j >= 0) && (j < NN);
  float dd = 0.f;
  if (valid) {
    const float* yrow = &ylds[j * YST];
    float ax = 0.f, ay = 0.f, az = 0.f, aww = 0.f;
    #pragma unroll
    for (int k = 0; k < DQ; ++k) {
      float4 v = *(const float4*)(yrow + 4 * k);
      ax  = fmaf(xr[k].x, v.x, ax);
      ay  = fmaf(xr[k].y, v.y, ay);
      az  = fmaf(xr[k].z, v.z, az);
      aww = fmaf(xr[k].w, v.w, aww);
    }
    float dot = (ax + ay) + (az + aww);
    dd = fmaf(-2.f, dot, xx + yrow[DD]);
  }
  float p1m1 = a1[t];
  float p2m1 = a2[t];
  if (t == 0) p2m1 = (d == 0) ? 0.f : BIGF;
  float m = fminf(fminf(p2m1, p1m1), myP1);
  float s = __expf(m - p2m1) + __expf(m - p1m1) + __expf(m - myP1);
  float sm = m - __logf(s);
  float cur = valid ? (dd + sm) : BIGF;
  aw[t + 1] = cur;
  myP1 = cur;
  __syncthreads();
}

__global__ __launch_bounds__(512, 2)
void dtw_fallback_kernel(const float* __restrict__ X, const float* __restrict__ Y,
                         float* __restrict__ loss)
{
  __shared__ float ylds[NN * YST];
  __shared__ float diag[3][NN + 1];

  const int b = blockIdx.x;
  const int t = threadIdx.x;

  const float4* Y4 = (const float4*)(Y + (size_t)b * NN * DD);
  for (int idx = t; idx < NN * DQ; idx += NN) {
    float4 v = Y4[idx];
    *(float4*)&ylds[(idx >> 4) * YST + (idx & 15) * 4] = v;
  }
  diag[0][t + 1] = BIGF; diag[1][t + 1] = BIGF; diag[2][t + 1] = BIGF;
  if (t == 0) { diag[0][0] = BIGF; diag[1][0] = BIGF; diag[2][0] = BIGF; }
  __syncthreads();

  float4 xr[DQ];
  float xx = 0.f;
  const float4* X4 = (const float4*)(X + (size_t)b * NN * DD + (size_t)t * DD);
  #pragma unroll
  for (int k = 0; k < DQ; ++k) {
    float4 v = X4[k];
    xr[k] = v;
    xx += v.x * v.x + v.y * v.y + v.z * v.z + v.w * v.w;
  }
  {
    float s = 0.f;
    const float* yrow = &ylds[t * YST];
    #pragma unroll
    for (int k = 0; k < DQ; ++k) {
      float4 v = *(const float4*)(yrow + 4 * k);
      s += v.x * v.x + v.y * v.y + v.z * v.z + v.w * v.w;
    }
    ylds[t * YST + DD] = s;
  }
  __syncthreads();

  float myP1 = BIGF;
  for (int dbase = 0; dbase < 2 * NN - 1; dbase += 3) {
    fb_step(dbase,     t, xr, xx, ylds, diag[2], diag[1], diag[0], myP1);
    fb_step(dbase + 1, t, xr, xx, ylds, diag[0], diag[2], diag[1], myP1);
    fb_step(dbase + 2, t, xr, xx, ylds, diag[1], diag[0], diag[2], myP1);
  }
  if (t == NN - 1) loss[b] = myP1;
}

// ======================= mean =======================
__global__ void mean_kernel(const float* __restrict__ loss, float* __restrict__ out, int B)
{
  const int t = threadIdx.x;
  float v = (t < B) ? loss[t] : 0.f;
  #pragma unroll
  for (int off = 32; off; off >>= 1) v += __shfl_down(v, off);
  if (t == 0) out[0] = v / (float)B;
}

extern "C" void kernel_launch(void* const* d_in, const int* in_sizes, int n_in,
                              void* d_out, int out_size, void* d_ws, size_t ws_size,
                              hipStream_t stream)
{
  const float* X = (const float*)d_in[0];
  const float* Y = (const float*)d_in[1];
  float* out = (float*)d_out;
  float* ws  = (float*)d_ws;

  const int B = in_sizes[0] / (NN * DD);   // 64

  const size_t skew_bytes = (size_t)B * (2 * NN - 1) * NN * sizeof(float);
  const size_t need = skew_bytes + 256;

  if (ws_size >= need) {
    float* loss = ws;                 // B floats
    float* skew = ws + 64;            // 256B offset
    delta_kernel<<<dim3(NN / TS, NN / TS, B), 256, 0, stream>>>(X, Y, skew);
    dp_kernel<<<B, 256, 0, stream>>>(skew, loss);
    mean_kernel<<<1, 64, 0, stream>>>(loss, out, B);
  } else {
    dtw_fallback_kernel<<<B, NN, 0, stream>>>(X, Y, ws);
    mean_kernel<<<1, 64, 0, stream>>>(ws, out, B);
  }
}